// Round 1
// baseline (532.037 us; speedup 1.0000x reference)
//
#include <hip/hip_runtime.h>

#define DIM_IN 256
#define DIM_H  64
#define SEQ_LEN 512
#define TPB 8   // row-tiles (64 rows each) per prepass block

static_assert(SEQ_LEN % 16 == 0, "tb structure assumes SEQ_LEN % 16 == 0");

typedef _Float16 h2_t  __attribute__((ext_vector_type(2)));
typedef _Float16 h8_t  __attribute__((ext_vector_type(8)));
typedef float    f32x4 __attribute__((ext_vector_type(4)));
union H8 { h8_t v; h2_t p[4]; };

// addrspace(1) pointers: loads/stores emit global_* (vmcnt-only), never flat_*.
typedef const __attribute__((address_space(1))) unsigned* gcu32_p;
typedef const __attribute__((address_space(1))) float*    gcf32_p;
typedef       __attribute__((address_space(1))) float*    gf32_p;

__device__ inline float dot2(h2_t a, h2_t b, float c) {
#if __has_builtin(__builtin_amdgcn_fdot2)
    return __builtin_amdgcn_fdot2(a, b, c, false);
#else
    return c + (float)a[0] * (float)b[0] + (float)a[1] * (float)b[1];
#endif
}
__device__ inline float exp2_(float x) {
#if __has_builtin(__builtin_amdgcn_exp2f)
    return __builtin_amdgcn_exp2f(x);
#else
    return exp2f(x);
#endif
}
__device__ inline float rcp_(float x) {
#if __has_builtin(__builtin_amdgcn_rcpf)
    return __builtin_amdgcn_rcpf(x);
#else
    return __fdividef(1.f, x);
#endif
}

// ---------------------------------------------------------------------------
// Pass 1 (MFMA): x-projections. Retiled: 8 row-tiles per block so the 192
// scalar weight loads amortize 8x; X double-buffered through registers.
// Outputs pre-scaled for the recurrence's exp2-based gates:
//   xur.x = -log2(e)*(xu+bu), xur.y = -log2(e)*(xr+br)   (packed f16x2)
//   xi    =  2*log2(e)*(xi+bi)  stored f32 directly into `out`
//   (rec reads xi[t] >=8 steps before it overwrites out[t] -- proven safe
//    ordering, same trick as the old XI16=0 path)
// ---------------------------------------------------------------------------
__global__ __launch_bounds__(256, 1)
void gru_prepass_mfma(const float* __restrict__ X,
                      const float* __restrict__ W_input,  const float* __restrict__ b_input,
                      const float* __restrict__ W_update, const float* __restrict__ b_update,
                      const float* __restrict__ W_reset,  const float* __restrict__ b_reset,
                      unsigned* __restrict__ xur_out, float* __restrict__ xi_out)
{
    const int tid  = threadIdx.x;
    const int lane = tid & 63;
    const int wv   = tid >> 6;
    const int q    = lane >> 4;
    const int m16  = lane & 15;

    constexpr int LDK = DIM_IN + 8;
    __shared__ _Float16 xs[64 * LDK];

    const int c = wv * 16 + m16;
    h8_t bu[8], brf[8], bif[8];
#pragma unroll
    for (int kt = 0; kt < 8; ++kt) {
        h8_t u, r, i;
#pragma unroll
        for (int jj = 0; jj < 8; ++jj) {
            const int k = kt * 32 + q * 8 + jj;
            u[jj] = (_Float16)W_update[k * DIM_H + c];
            r[jj] = (_Float16)W_reset [k * DIM_H + c];
            i[jj] = (_Float16)W_input [k * DIM_H + c];
        }
        bu[kt] = u; brf[kt] = r; bif[kt] = i;
    }
    const float bzc = b_update[c], brc = b_reset[c], bic = b_input[c];

    const int tile0 = blockIdx.x * TPB;
    float4 pf[16];
    {
        const float4* xb = (const float4*)(X + (size_t)tile0 * 64 * DIM_IN);
#pragma unroll
        for (int i = 0; i < 16; ++i) pf[i] = xb[tid + 256 * i];
    }

#pragma unroll 1
    for (int tI = 0; tI < TPB; ++tI) {
        // stage current tile to LDS (f32 -> f16)
#pragma unroll
        for (int i = 0; i < 16; ++i) {
            const int f   = tid + 256 * i;
            const int row = f >> 6;
            const int kq  = f & 63;
            const float4 v = pf[i];
            h2_t a, b2;
            a[0]  = (_Float16)v.x; a[1]  = (_Float16)v.y;
            b2[0] = (_Float16)v.z; b2[1] = (_Float16)v.w;
            _Float16* dst = &xs[row * LDK + kq * 4];
            *(h2_t*)dst = a; *(h2_t*)(dst + 2) = b2;
        }
        __syncthreads();
        // prefetch next tile (HBM latency hides under MFMA phase)
        if (tI + 1 < TPB) {
            const float4* xb = (const float4*)(X + (size_t)(tile0 + tI + 1) * 64 * DIM_IN);
#pragma unroll
            for (int i = 0; i < 16; ++i) pf[i] = xb[tid + 256 * i];
        }
        const size_t orow0 = (size_t)(tile0 + tI) * 64;
#pragma unroll
        for (int rt = 0; rt < 4; ++rt) {
            const int r0 = rt * 16;
            f32x4 au = {0.f,0.f,0.f,0.f}, ar = {0.f,0.f,0.f,0.f}, aa = {0.f,0.f,0.f,0.f};
#pragma unroll
            for (int kt = 0; kt < 8; ++kt) {
                const h8_t a = *(const h8_t*)&xs[(r0 + m16) * LDK + kt * 32 + q * 8];
                au = __builtin_amdgcn_mfma_f32_16x16x32_f16(a, bu[kt],  au, 0, 0, 0);
                ar = __builtin_amdgcn_mfma_f32_16x16x32_f16(a, brf[kt], ar, 0, 0, 0);
                aa = __builtin_amdgcn_mfma_f32_16x16x32_f16(a, bif[kt], aa, 0, 0, 0);
            }
#pragma unroll
            for (int i = 0; i < 4; ++i) {
                const size_t grow = orow0 + r0 + q * 4 + i;
                h2_t pk;
                pk[0] = (_Float16)(-1.44269504f * (au[i] + bzc));
                pk[1] = (_Float16)(-1.44269504f * (ar[i] + brc));
                xur_out[grow * DIM_H + c] = __builtin_bit_cast(unsigned, pk);
                xi_out[grow * DIM_H + c]  = 2.88539008f * (aa[i] + bic);
            }
        }
        __syncthreads();
    }
}

// ---------------------------------------------------------------------------
// Pass 2: recurrence. One wave per chain. Changes vs R5:
//  * NO lgkmcnt(0) fences: same-wave DS ops are processed in order by the LDS
//    pipe; same-array may-alias keeps compiler order. ds_reads issue in the
//    shadow of the ds_write.
//  * Gate-stream ring replaced by explicit 8-step double buffer: 16
//    global_load_dword issued via inline asm (invisible to the compiler's
//    waitcnt tracking, so no per-step drains), one hand-placed
//    s_waitcnt vmcnt(8) per 8 steps whose "+v" operands launder the loaded
//    regs (consumers are data-dependent on the wait).
//  * exp2-based gates on pre-scaled x-projections; hn = fma(z, th-h, h).
// ---------------------------------------------------------------------------

#define GLOAD8(R0,R1,R2,R3,R4,R5,R6,R7,ADDR)                        \
    __asm__ volatile(                                               \
        "global_load_dword %0, %8, off\n\t"                         \
        "global_load_dword %1, %8, off offset:256\n\t"              \
        "global_load_dword %2, %8, off offset:512\n\t"              \
        "global_load_dword %3, %8, off offset:768\n\t"              \
        "global_load_dword %4, %8, off offset:1024\n\t"             \
        "global_load_dword %5, %8, off offset:1280\n\t"             \
        "global_load_dword %6, %8, off offset:1536\n\t"             \
        "global_load_dword %7, %8, off offset:1792"                 \
        : "=&v"(R0), "=&v"(R1), "=&v"(R2), "=&v"(R3),               \
          "=&v"(R4), "=&v"(R5), "=&v"(R6), "=&v"(R7)                \
        : "v"(ADDR) : "memory")

// vmcnt(8): 16 prefetch loads (oldest) must retire; the <=8 newest og stores
// may stay in flight. "+v" ties the prefetched regs to this wait.
#define VMWAIT8(N,M)                                                \
    __asm__ volatile("s_waitcnt vmcnt(8)"                           \
        : "+v"(N##0), "+v"(N##1), "+v"(N##2), "+v"(N##3),           \
          "+v"(N##4), "+v"(N##5), "+v"(N##6), "+v"(N##7),           \
          "+v"(M##0), "+v"(M##1), "+v"(M##2), "+v"(M##3),           \
          "+v"(M##4), "+v"(M##5), "+v"(M##6), "+v"(M##7))

#define DOTZR(HX, Q)                                                \
    az0 = dot2(HX.p[0], wu[4*(Q)+0], az0);                          \
    ar0 = dot2(HX.p[0], wr[4*(Q)+0], ar0);                          \
    az1 = dot2(HX.p[1], wu[4*(Q)+1], az1);                          \
    ar1 = dot2(HX.p[1], wr[4*(Q)+1], ar1);                          \
    az2 = dot2(HX.p[2], wu[4*(Q)+2], az2);                          \
    ar2 = dot2(HX.p[2], wr[4*(Q)+2], ar2);                          \
    az3 = dot2(HX.p[3], wu[4*(Q)+3], az3);                          \
    ar3 = dot2(HX.p[3], wr[4*(Q)+3], ar3);

#define DOTI(SX, Q)                                                 \
    ax0 = dot2(SX.p[0], wi[4*(Q)+0], ax0);                          \
    ax1 = dot2(SX.p[1], wi[4*(Q)+1], ax1);                          \
    ax2 = dot2(SX.p[2], wi[4*(Q)+2], ax2);                          \
    ax3 = dot2(SX.p[3], wi[4*(Q)+3], ax3);

// One timestep. PF (prefetch asm) splices in after the h-broadcast reads so
// the 16 load issues overlap the ~120cy ds_read latency window.
#define GSTEP_CORE(T, PRU, XIV, PF) do {                                          \
    const h2_t pr_ = __builtin_bit_cast(h2_t, (PRU));                             \
    const float xu_ = (float)pr_[0];                                              \
    const float xr_ = (float)pr_[1];                                              \
    const H8* hp_ = (const H8*)hh;                                                \
    H8 hx0_ = hp_[0], hx1_ = hp_[1], hx2_ = hp_[2], hx3_ = hp_[3],                \
       hx4_ = hp_[4], hx5_ = hp_[5], hx6_ = hp_[6], hx7_ = hp_[7];                \
    PF;                                                                           \
    float az0=0.f,az1=0.f,az2=0.f,az3=0.f, ar0=0.f,ar1=0.f,ar2=0.f,ar3=0.f;       \
    DOTZR(hx0_,0) DOTZR(hx1_,1) DOTZR(hx2_,2) DOTZR(hx3_,3)                       \
    DOTZR(hx4_,4) DOTZR(hx5_,5) DOTZR(hx6_,6) DOTZR(hx7_,7)                       \
    const float dr_ = (ar0 + ar1) + (ar2 + ar3);                                  \
    const float rg_ = rcp_(1.f + exp2_(fmaf(dr_, -1.44269504f, xr_)));            \
    ss[j] = (_Float16)(hprev * rg_);                                              \
    const H8* sp_ = (const H8*)ss;                                                \
    H8 sx0_ = sp_[0], sx1_ = sp_[1], sx2_ = sp_[2], sx3_ = sp_[3],                \
       sx4_ = sp_[4], sx5_ = sp_[5], sx6_ = sp_[6], sx7_ = sp_[7];                \
    const float dz_ = (az0 + az1) + (az2 + az3);                                  \
    const float zg_ = rcp_(1.f + exp2_(fmaf(dz_, -1.44269504f, xu_)));            \
    float ax0=0.f,ax1=0.f,ax2=0.f,ax3=0.f;                                        \
    DOTI(sx0_,0) DOTI(sx1_,1) DOTI(sx2_,2) DOTI(sx3_,3)                           \
    DOTI(sx4_,4) DOTI(sx5_,5) DOTI(sx6_,6) DOTI(sx7_,7)                           \
    const float dx_ = (ax0 + ax1) + (ax2 + ax3);                                  \
    const float th_ = fmaf(-2.f, rcp_(1.f + exp2_(fmaf(dx_, 2.88539008f, (XIV)))), 1.f); \
    const float hn_ = fmaf(zg_, th_ - hprev, hprev);                              \
    hh[j] = (_Float16)hn_;                                                        \
    og[(size_t)(T) * DIM_H] = hn_;                                                \
    hprev = hn_;                                                                  \
} while (0)

#define GSTEP(T, PRU, XIV) GSTEP_CORE(T, PRU, XIV, (void)0)

// 8 steps consuming buffer C/D, prefetching the next 8 slots into N/M.
#define TB_PF(T0, C, D, N, M) do {                                                \
    const unsigned long long axu_ = (unsigned long long)(xg + (size_t)((T0) + 8) * DIM_H); \
    const unsigned long long axi_ = (unsigned long long)(ig + (size_t)((T0) + 8) * DIM_H); \
    GSTEP_CORE((T0) + 0, C##0, D##0,                                              \
        GLOAD8(N##0,N##1,N##2,N##3,N##4,N##5,N##6,N##7, axu_);                    \
        GLOAD8(M##0,M##1,M##2,M##3,M##4,M##5,M##6,M##7, axi_));                   \
    GSTEP((T0) + 1, C##1, D##1);                                                  \
    GSTEP((T0) + 2, C##2, D##2);                                                  \
    GSTEP((T0) + 3, C##3, D##3);                                                  \
    GSTEP((T0) + 4, C##4, D##4);                                                  \
    GSTEP((T0) + 5, C##5, D##5);                                                  \
    GSTEP((T0) + 6, C##6, D##6);                                                  \
    GSTEP((T0) + 7, C##7, D##7);                                                  \
    VMWAIT8(N, M);                                                                \
} while (0)

__global__ __launch_bounds__(64, 1)
void gru_rec(const unsigned* __restrict__ xur, const float* xi,
             const float* __restrict__ W_input, const float* __restrict__ W_update,
             const float* __restrict__ W_reset,
             float* out)
{
    const int b = blockIdx.x;
    const int j = threadIdx.x;

    __shared__ __align__(16) _Float16 hh[DIM_H];
    __shared__ __align__(16) _Float16 ss[DIM_H];

    h2_t wu[32], wr[32], wi[32];
#pragma unroll
    for (int m = 0; m < 32; ++m) {
        const int k = DIM_IN + 2 * m;
        h2_t a, cc, d;
        a[0]  = (_Float16)W_update[(k    ) * DIM_H + j];
        a[1]  = (_Float16)W_update[(k + 1) * DIM_H + j];
        cc[0] = (_Float16)W_reset [(k    ) * DIM_H + j];
        cc[1] = (_Float16)W_reset [(k + 1) * DIM_H + j];
        d[0]  = (_Float16)W_input [(k    ) * DIM_H + j];
        d[1]  = (_Float16)W_input [(k + 1) * DIM_H + j];
        wu[m] = a; wr[m] = cc; wi[m] = d;
    }

    hh[j] = (_Float16)0.f;
    float hprev = 0.f;

    const size_t base = (size_t)b * SEQ_LEN * DIM_H + j;
    gcu32_p xg = (gcu32_p)(xur + base);
    gcf32_p ig = (gcf32_p)(xi + base);
    gf32_p  og = (gf32_p)(out + base);

    unsigned au0,au1,au2,au3,au4,au5,au6,au7;
    float    ai0,ai1,ai2,ai3,ai4,ai5,ai6,ai7;
    unsigned bu0,bu1,bu2,bu3,bu4,bu5,bu6,bu7;
    float    bi0,bi1,bi2,bi3,bi4,bi5,bi6,bi7;

    // prologue: plain (compiler-tracked) loads of slots 0..7
    au0 = xg[0*DIM_H]; au1 = xg[1*DIM_H]; au2 = xg[2*DIM_H]; au3 = xg[3*DIM_H];
    au4 = xg[4*DIM_H]; au5 = xg[5*DIM_H]; au6 = xg[6*DIM_H]; au7 = xg[7*DIM_H];
    ai0 = ig[0*DIM_H]; ai1 = ig[1*DIM_H]; ai2 = ig[2*DIM_H]; ai3 = ig[3*DIM_H];
    ai4 = ig[4*DIM_H]; ai5 = ig[5*DIM_H]; ai6 = ig[6*DIM_H]; ai7 = ig[7*DIM_H];

#pragma unroll 1
    for (int t0 = 0; t0 < SEQ_LEN - 16; t0 += 16) {
        TB_PF(t0,     au, ai, bu, bi);
        TB_PF(t0 + 8, bu, bi, au, ai);
    }
    TB_PF(SEQ_LEN - 16, au, ai, bu, bi);   // t0=496, prefetch 504..511 into b*
    GSTEP(SEQ_LEN - 8 + 0, bu0, bi0);
    GSTEP(SEQ_LEN - 8 + 1, bu1, bi1);
    GSTEP(SEQ_LEN - 8 + 2, bu2, bi2);
    GSTEP(SEQ_LEN - 8 + 3, bu3, bi3);
    GSTEP(SEQ_LEN - 8 + 4, bu4, bi4);
    GSTEP(SEQ_LEN - 8 + 5, bu5, bi5);
    GSTEP(SEQ_LEN - 8 + 6, bu6, bi6);
    GSTEP(SEQ_LEN - 8 + 7, bu7, bi7);
}

extern "C" void kernel_launch(void* const* d_in, const int* in_sizes, int n_in,
                              void* d_out, int out_size, void* d_ws, size_t ws_size,
                              hipStream_t stream) {
    const float* inputs   = (const float*)d_in[0];
    const float* W_input  = (const float*)d_in[1];
    const float* b_input  = (const float*)d_in[2];
    const float* W_update = (const float*)d_in[3];
    const float* b_update = (const float*)d_in[4];
    const float* W_reset  = (const float*)d_in[5];
    const float* b_reset  = (const float*)d_in[6];
    float* out = (float*)d_out;

    const int batch = in_sizes[0] / (SEQ_LEN * DIM_IN);

    unsigned* xur_w = (unsigned*)d_ws;   // rows*64*4 B (33.5 MB @ batch=256)

    // xi (f32, pre-scaled) goes straight into `out`: rec reads slot t+8
    // before it ever writes slot t, and the prepass rewrites it every replay.
    gru_prepass_mfma<<<batch, 256, 0, stream>>>(
        inputs, W_input, b_input, W_update, b_update, W_reset, b_reset,
        xur_w, out);
    gru_rec<<<batch, 64, 0, stream>>>(xur_w, out,
                                      W_input, W_update, W_reset, out);
}

// Round 2
// 422.495 us; speedup vs baseline: 1.2593x; 1.2593x over previous
//
#include <hip/hip_runtime.h>

#define DIM_IN 256
#define DIM_H  64
#define SEQ_LEN 512
#define TPB 4   // row-tiles (64 rows each) per prepass block

typedef _Float16 h2_t  __attribute__((ext_vector_type(2)));
typedef _Float16 h8_t  __attribute__((ext_vector_type(8)));
typedef float    f32x4 __attribute__((ext_vector_type(4)));
union H8 { h8_t v; h2_t p[4]; };

// addrspace(1) pointers: loads/stores emit global_* (vmcnt-only), never flat_*.
typedef const __attribute__((address_space(1))) unsigned* gcu32_p;
typedef const __attribute__((address_space(1))) _Float16* gch16_p;
typedef const __attribute__((address_space(1))) float*    gcf32_p;
typedef       __attribute__((address_space(1))) float*    gf32_p;

__device__ inline float dot2(h2_t a, h2_t b, float c) {
#if __has_builtin(__builtin_amdgcn_fdot2)
    return __builtin_amdgcn_fdot2(a, b, c, false);
#else
    return c + (float)a[0] * (float)b[0] + (float)a[1] * (float)b[1];
#endif
}
__device__ inline float exp2_(float x) {
#if __has_builtin(__builtin_amdgcn_exp2f)
    return __builtin_amdgcn_exp2f(x);
#else
    return exp2f(x);
#endif
}
__device__ inline float rcp_(float x) {
#if __has_builtin(__builtin_amdgcn_rcpf)
    return __builtin_amdgcn_rcpf(x);
#else
    return __fdividef(1.f, x);
#endif
}

// lgkm-only fence: orders LDS ops without draining the vm prefetch stream.
#define LDS_FENCE() __asm__ volatile("s_waitcnt lgkmcnt(0)" ::: "memory")

// ---------------------------------------------------------------------------
// Pass 1 (MFMA): x-projections, weights amortized over TPB tiles, X tile
// double-buffered through registers. Outputs pre-scaled for exp2 gates:
//   xur.x = -log2(e)*(xu+bu), xur.y = -log2(e)*(xr+br)   (packed f16x2)
//   xi    =  2*log2(e)*(xi+bi)   (f16 into ws if it fits, else f32 into out)
// __launch_bounds__(256,2): VGPR<=256 so two blocks can co-reside per CU.
// ---------------------------------------------------------------------------
template <int XI16>
__global__ __launch_bounds__(256, 2)
void gru_prepass_mfma(const float* __restrict__ X,
                      const float* __restrict__ W_input,  const float* __restrict__ b_input,
                      const float* __restrict__ W_update, const float* __restrict__ b_update,
                      const float* __restrict__ W_reset,  const float* __restrict__ b_reset,
                      unsigned* __restrict__ xur_out,
                      _Float16* __restrict__ xi16_out, float* __restrict__ xi32_out)
{
    const int tid  = threadIdx.x;
    const int lane = tid & 63;
    const int wv   = tid >> 6;
    const int q    = lane >> 4;
    const int m16  = lane & 15;

    constexpr int LDK = DIM_IN + 8;
    __shared__ _Float16 xs[64 * LDK];

    const int c = wv * 16 + m16;
    h8_t bu[8], brf[8], bif[8];
#pragma unroll
    for (int kt = 0; kt < 8; ++kt) {
        h8_t u, r, i;
#pragma unroll
        for (int jj = 0; jj < 8; ++jj) {
            const int k = kt * 32 + q * 8 + jj;
            u[jj] = (_Float16)W_update[k * DIM_H + c];
            r[jj] = (_Float16)W_reset [k * DIM_H + c];
            i[jj] = (_Float16)W_input [k * DIM_H + c];
        }
        bu[kt] = u; brf[kt] = r; bif[kt] = i;
    }
    const float bzc = b_update[c], brc = b_reset[c], bic = b_input[c];

    const int tile0 = blockIdx.x * TPB;
    float4 pf[16];
    {
        const float4* xb = (const float4*)(X + (size_t)tile0 * 64 * DIM_IN);
#pragma unroll
        for (int i = 0; i < 16; ++i) pf[i] = xb[tid + 256 * i];
    }

#pragma unroll 1
    for (int tI = 0; tI < TPB; ++tI) {
        // stage current tile to LDS (f32 -> f16)
#pragma unroll
        for (int i = 0; i < 16; ++i) {
            const int f   = tid + 256 * i;
            const int row = f >> 6;
            const int kq  = f & 63;
            const float4 v = pf[i];
            h2_t a, b2;
            a[0]  = (_Float16)v.x; a[1]  = (_Float16)v.y;
            b2[0] = (_Float16)v.z; b2[1] = (_Float16)v.w;
            _Float16* dst = &xs[row * LDK + kq * 4];
            *(h2_t*)dst = a; *(h2_t*)(dst + 2) = b2;
        }
        __syncthreads();
        // prefetch next tile (HBM latency hides under the MFMA phase)
        if (tI + 1 < TPB) {
            const float4* xb = (const float4*)(X + (size_t)(tile0 + tI + 1) * 64 * DIM_IN);
#pragma unroll
            for (int i = 0; i < 16; ++i) pf[i] = xb[tid + 256 * i];
        }
        const size_t orow0 = (size_t)(tile0 + tI) * 64;
#pragma unroll
        for (int rt = 0; rt < 4; ++rt) {
            const int r0 = rt * 16;
            f32x4 au = {0.f,0.f,0.f,0.f}, ar = {0.f,0.f,0.f,0.f}, aa = {0.f,0.f,0.f,0.f};
#pragma unroll
            for (int kt = 0; kt < 8; ++kt) {
                const h8_t a = *(const h8_t*)&xs[(r0 + m16) * LDK + kt * 32 + q * 8];
                au = __builtin_amdgcn_mfma_f32_16x16x32_f16(a, bu[kt],  au, 0, 0, 0);
                ar = __builtin_amdgcn_mfma_f32_16x16x32_f16(a, brf[kt], ar, 0, 0, 0);
                aa = __builtin_amdgcn_mfma_f32_16x16x32_f16(a, bif[kt], aa, 0, 0, 0);
            }
#pragma unroll
            for (int i = 0; i < 4; ++i) {
                const size_t grow = orow0 + r0 + q * 4 + i;
                h2_t pk;
                pk[0] = (_Float16)(-1.44269504f * (au[i] + bzc));
                pk[1] = (_Float16)(-1.44269504f * (ar[i] + brc));
                xur_out[grow * DIM_H + c] = __builtin_bit_cast(unsigned, pk);
                const float xiv = 2.88539008f * (aa[i] + bic);
                if (XI16) xi16_out[grow * DIM_H + c] = (_Float16)xiv;
                else      xi32_out[grow * DIM_H + c] = xiv;
            }
        }
        __syncthreads();
    }
}

// ---------------------------------------------------------------------------
// Pass 2: recurrence — R5-proven skeleton (compiler-tracked ring-8, lgkm-only
// fences, unroll 8, AS1 global traffic) with two changes:
//  * amdgpu_waves_per_eu(1,1): opens the VGPR budget to 512 so the 96 VGPRs
//    of loop-invariant gate weights stay register-resident instead of being
//    rematerialized from L2 every step (R1 evidence: VGPR_Count=92 < the 96
//    weight registers alone). Occupancy is already 1 wave/CU -> no cost.
//  * r-gate-first ordering: compute r dots, write ss, issue ss reads, then
//    do the z dots from the already-live hx registers so the second LDS
//    roundtrip hides under z work.
// ---------------------------------------------------------------------------

#define DOTR(HX, Q)                                                 \
    ar0 = dot2(HX.p[0], wr[4*(Q)+0], ar0);                          \
    ar1 = dot2(HX.p[1], wr[4*(Q)+1], ar1);                          \
    ar2 = dot2(HX.p[2], wr[4*(Q)+2], ar2);                          \
    ar3 = dot2(HX.p[3], wr[4*(Q)+3], ar3);

#define DOTZ(HX, Q)                                                 \
    az0 = dot2(HX.p[0], wu[4*(Q)+0], az0);                          \
    az1 = dot2(HX.p[1], wu[4*(Q)+1], az1);                          \
    az2 = dot2(HX.p[2], wu[4*(Q)+2], az2);                          \
    az3 = dot2(HX.p[3], wu[4*(Q)+3], az3);

#define DOTI(SX, Q)                                                 \
    ax0 = dot2(SX.p[0], wi[4*(Q)+0], ax0);                          \
    ax1 = dot2(SX.p[1], wi[4*(Q)+1], ax1);                          \
    ax2 = dot2(SX.p[2], wi[4*(Q)+2], ax2);                          \
    ax3 = dot2(SX.p[3], wi[4*(Q)+3], ax3);

template <int XI16>
__global__
__attribute__((amdgpu_flat_work_group_size(64, 64)))
__attribute__((amdgpu_waves_per_eu(1, 1)))
void gru_rec(const unsigned* __restrict__ xur, const _Float16* __restrict__ xi16,
             const float* __restrict__ xif,
             const float* __restrict__ W_input, const float* __restrict__ W_update,
             const float* __restrict__ W_reset,
             float* __restrict__ out)
{
    const int b = blockIdx.x;
    const int j = threadIdx.x;

    __shared__ __align__(16) _Float16 hh[DIM_H];
    __shared__ __align__(16) _Float16 ss[DIM_H];

    h2_t wu[32], wr[32], wi[32];
#pragma unroll
    for (int m = 0; m < 32; ++m) {
        const int k = DIM_IN + 2 * m;
        h2_t a, cc, d;
        a[0]  = (_Float16)W_update[(k    ) * DIM_H + j];
        a[1]  = (_Float16)W_update[(k + 1) * DIM_H + j];
        cc[0] = (_Float16)W_reset [(k    ) * DIM_H + j];
        cc[1] = (_Float16)W_reset [(k + 1) * DIM_H + j];
        d[0]  = (_Float16)W_input [(k    ) * DIM_H + j];
        d[1]  = (_Float16)W_input [(k + 1) * DIM_H + j];
        wu[m] = a; wr[m] = cc; wi[m] = d;
    }

    hh[j] = (_Float16)0.f;
    float hprev = 0.f;

    const size_t base = (size_t)b * SEQ_LEN * DIM_H + j;
    gcu32_p xg  = (gcu32_p)(xur + base);
    gch16_p ig  = (gch16_p)(xi16 + base);
    gcf32_p igf = (gcf32_p)(xif + base);     // xi source when XI16 == 0
    gf32_p  og  = (gf32_p)(out + base);

    unsigned ru[8];
    float    rxi[8];
#pragma unroll
    for (int d = 0; d < 8; ++d) {
        ru[d]  = xg[(size_t)d * DIM_H];
        rxi[d] = XI16 ? (float)ig[(size_t)d * DIM_H] : igf[(size_t)d * DIM_H];
    }
    LDS_FENCE();

#pragma unroll 1
    for (int tb = 0; tb < SEQ_LEN / 8; ++tb) {
#pragma unroll
        for (int u = 0; u < 8; ++u) {
            const int t = tb * 8 + u;
            // consume ring slot (loaded 8 steps ago), refill for t+8
            const h2_t pr = __builtin_bit_cast(h2_t, ru[u]);
            const float xu = (float)pr[0];
            const float xr = (float)pr[1];
            const float xi = rxi[u];
            const int tp = (t + 8 < SEQ_LEN) ? t + 8 : SEQ_LEN - 1;
            ru[u]  = xg[(size_t)tp * DIM_H];
            rxi[u] = XI16 ? (float)ig[(size_t)tp * DIM_H] : igf[(size_t)tp * DIM_H];

            // broadcast-read h (8 x b128), keep live for both r and z dots
            const H8* hp = (const H8*)hh;
            H8 hx0 = hp[0], hx1 = hp[1], hx2 = hp[2], hx3 = hp[3],
               hx4 = hp[4], hx5 = hp[5], hx6 = hp[6], hx7 = hp[7];

            // phase A: r-gate only -> ss write as early as possible
            float ar0 = 0.f, ar1 = 0.f, ar2 = 0.f, ar3 = 0.f;
            DOTR(hx0,0) DOTR(hx1,1) DOTR(hx2,2) DOTR(hx3,3)
            DOTR(hx4,4) DOTR(hx5,5) DOTR(hx6,6) DOTR(hx7,7)
            const float rg = rcp_(1.f + exp2_(
                fmaf((ar0 + ar1) + (ar2 + ar3), -1.44269504f, xr)));
            ss[j] = (_Float16)(hprev * rg);
            LDS_FENCE();

            // phase B: issue ss reads, hide their latency under the z dots
            const H8* sp = (const H8*)ss;
            H8 sx0 = sp[0], sx1 = sp[1], sx2 = sp[2], sx3 = sp[3],
               sx4 = sp[4], sx5 = sp[5], sx6 = sp[6], sx7 = sp[7];

            float az0 = 0.f, az1 = 0.f, az2 = 0.f, az3 = 0.f;
            DOTZ(hx0,0) DOTZ(hx1,1) DOTZ(hx2,2) DOTZ(hx3,3)
            DOTZ(hx4,4) DOTZ(hx5,5) DOTZ(hx6,6) DOTZ(hx7,7)
            const float zg = rcp_(1.f + exp2_(
                fmaf((az0 + az1) + (az2 + az3), -1.44269504f, xu)));

            // phase C: candidate
            float ax0 = 0.f, ax1 = 0.f, ax2 = 0.f, ax3 = 0.f;
            DOTI(sx0,0) DOTI(sx1,1) DOTI(sx2,2) DOTI(sx3,3)
            DOTI(sx4,4) DOTI(sx5,5) DOTI(sx6,6) DOTI(sx7,7)
            const float th = fmaf(-2.f, rcp_(1.f + exp2_(
                fmaf((ax0 + ax1) + (ax2 + ax3), 2.88539008f, xi))), 1.f);

            const float hn = fmaf(zg, th - hprev, hprev);
            hh[j] = (_Float16)hn;
            LDS_FENCE();
            og[(size_t)t * DIM_H] = hn;    // vmcnt-only, fire-and-forget
            hprev = hn;
        }
    }
}

extern "C" void kernel_launch(void* const* d_in, const int* in_sizes, int n_in,
                              void* d_out, int out_size, void* d_ws, size_t ws_size,
                              hipStream_t stream) {
    const float* inputs   = (const float*)d_in[0];
    const float* W_input  = (const float*)d_in[1];
    const float* b_input  = (const float*)d_in[2];
    const float* W_update = (const float*)d_in[3];
    const float* b_update = (const float*)d_in[4];
    const float* W_reset  = (const float*)d_in[5];
    const float* b_reset  = (const float*)d_in[6];
    float* out = (float*)d_out;

    const int    batch = in_sizes[0] / (SEQ_LEN * DIM_IN);
    const size_t rows  = (size_t)batch * SEQ_LEN;
    const int    nblk  = (int)(rows / 64 / TPB);

    unsigned* xur_w = (unsigned*)d_ws;                       // rows*64*4 B
    _Float16* xi_w  = (_Float16*)(xur_w + rows * DIM_H);     // rows*64*2 B
    const bool xi16 = ws_size >= rows * DIM_H * 6ull;        // 50.3 MB (proven R3/R4)

    if (xi16) {
        gru_prepass_mfma<1><<<nblk, 256, 0, stream>>>(
            inputs, W_input, b_input, W_update, b_update, W_reset, b_reset,
            xur_w, xi_w, out);
        gru_rec<1><<<batch, 64, 0, stream>>>(xur_w, xi_w, out,
                                             W_input, W_update, W_reset, out);
    } else {
        // xi f32 lives in `out`: rec reads slot t+8 before it writes slot t
        gru_prepass_mfma<0><<<nblk, 256, 0, stream>>>(
            inputs, W_input, b_input, W_update, b_update, W_reset, b_reset,
            xur_w, xi_w, out);
        gru_rec<0><<<batch, 64, 0, stream>>>(xur_w, xi_w, out,
                                             W_input, W_update, W_reset, out);
    }
}